// Round 6
// baseline (270.753 us; speedup 1.0000x reference)
//
#include <hip/hip_runtime.h>

typedef unsigned int u32;
typedef unsigned short u16;
typedef __bf16 bf16x8 __attribute__((ext_vector_type(8)));
typedef float floatx4 __attribute__((ext_vector_type(4)));
typedef _Float16 f16x4 __attribute__((ext_vector_type(4)));

// ---- helpers ----------------------------------------------------------------

// fp32 -> bf16 bits, round-to-nearest-even
__device__ __forceinline__ u16 f2b(float f) {
    u32 u = __float_as_uint(f);
    u = u + 0x7fffu + ((u >> 16) & 1u);
    return (u16)(u >> 16);
}

// pack 4 fp32 -> f16x4 via scalar v_cvt_f16_f32
__device__ __forceinline__ f16x4 pack4h(float a, float b, float c, float d) {
    f16x4 v;
    v[0] = (_Float16)a; v[1] = (_Float16)b;
    v[2] = (_Float16)c; v[3] = (_Float16)d;
    return v;
}

// async global->LDS 16B copy (lane-linear LDS dest required)
__device__ __forceinline__ void async_copy16(const void* g, void* l) {
    __builtin_amdgcn_global_load_lds(
        (__attribute__((address_space(1))) u32*)g,
        (__attribute__((address_space(3))) u32*)l, 16, 0, 0);
}

// ---- merged cast kernel -----------------------------------------------------
// x: 2097152 float4 | Wqkv: 786432 | Wproj: 262144  (total 3145728)

__global__ void cast_all_kernel(const float4* __restrict__ x,
                                const float4* __restrict__ wq,
                                const float4* __restrict__ wp,
                                ushort4* __restrict__ xb,
                                ushort4* __restrict__ wqb,
                                ushort4* __restrict__ wpb) {
    int i = blockIdx.x * 256 + threadIdx.x;
    const float4* s;
    ushort4* d;
    int off;
    if (i < 2097152) { s = x; d = xb; off = i; }
    else if (i < 2883584) { s = wq; d = wqb; off = i - 2097152; }
    else { s = wp; d = wpb; off = i - 2883584; }
    float4 v = s[off];
    ushort4 o;
    o.x = f2b(v.x); o.y = f2b(v.y); o.z = f2b(v.z); o.w = f2b(v.w);
    d[off] = o;
}

// ---- GEMM 1: qkv = x @ Wqkv^T -----------------------------------------------
// Q,K thirds -> qkvsep [2][8][16][1024][64] bf16 (natural).
// V third    -> Vt [8][16][64][1024] f16 (transposed, 8B packed stores).

__global__ __launch_bounds__(256) void gemm_qkv_kernel(
    const u16* __restrict__ A, const u16* __restrict__ W,
    u16* __restrict__ qkvsep, u16* __restrict__ Vt) {
    constexpr int K = 1024;
    __shared__ u16 sA[128 * 32];
    __shared__ u16 sB[128 * 32];
    const int t = threadIdx.x;
    const int wave = t >> 6, lane = t & 63;
    const int quad = lane >> 4, l16 = lane & 15;
    const int wr = wave >> 1, wc = wave & 1;
    const int m0 = blockIdx.x * 128;
    const int n0 = blockIdx.y * 128;

    floatx4 acc[4][4];
#pragma unroll
    for (int i = 0; i < 4; i++)
#pragma unroll
        for (int j = 0; j < 4; j++)
#pragma unroll
            for (int r = 0; r < 4; r++) acc[i][j][r] = 0.f;

    for (int k0 = 0; k0 < K; k0 += 32) {
        __syncthreads();
#pragma unroll
        for (int i = 0; i < 2; ++i) {
            const int idx = i * 256 + t;
            const int r_ = idx >> 2;
            const int c8 = (idx & 3) * 8;
            async_copy16(A + (size_t)(m0 + r_) * K + k0 + c8, &sA[r_ * 32 + c8]);
            async_copy16(W + (size_t)(n0 + r_) * K + k0 + c8, &sB[r_ * 32 + c8]);
        }
        __syncthreads();
        bf16x8 af[4], bw[4];
#pragma unroll
        for (int i = 0; i < 4; i++)
            af[i] = *(const bf16x8*)&sA[(wr * 64 + i * 16 + l16) * 32 + quad * 8];
#pragma unroll
        for (int j = 0; j < 4; j++)
            bw[j] = *(const bf16x8*)&sB[(wc * 64 + j * 16 + l16) * 32 + quad * 8];
#pragma unroll
        for (int i = 0; i < 4; i++)
#pragma unroll
            for (int j = 0; j < 4; j++)
                acc[i][j] = __builtin_amdgcn_mfma_f32_16x16x32_bf16(
                    af[i], bw[j], acc[i][j], 0, 0, 0);
    }
    if (n0 >= 2048) {
        // V third: write transposed f16 Vt[bh][e][n]
#pragma unroll
        for (int i = 0; i < 4; i++) {
#pragma unroll
            for (int j = 0; j < 4; j++) {
                const int n = n0 + wc * 64 + j * 16 + l16;
                const int h = (n >> 6) & 15, e = n & 63;
                const int m = m0 + wr * 64 + i * 16 + quad * 4;
                const int b = m >> 10, nn = m & 1023;
                f16x4 v = pack4h(acc[i][j][0], acc[i][j][1],
                                 acc[i][j][2], acc[i][j][3]);
                *(f16x4*)(Vt + (((size_t)(b * 16 + h) * 64 + e) * 1024 + nn)) = v;
            }
        }
    } else {
#pragma unroll
        for (int i = 0; i < 4; i++) {
#pragma unroll
            for (int j = 0; j < 4; j++) {
                const int n = n0 + wc * 64 + j * 16 + l16;
                const int tsel = n >> 10, h = (n >> 6) & 15, e = n & 63;
#pragma unroll
                for (int r = 0; r < 4; r++) {
                    const int m = m0 + wr * 64 + i * 16 + quad * 4 + r;
                    const int b = m >> 10, nn = m & 1023;
                    const size_t dst =
                        ((((size_t)tsel * 8 + b) * 16 + h) * 1024 + nn) * 64 + e;
                    qkvsep[dst] = f2b(acc[i][j][r]);
                }
            }
        }
    }
}

// ---- GEMM 2: out = O @ Wproj^T + bias, fp32 out -----------------------------

__global__ __launch_bounds__(256) void gemm_proj_kernel(
    const u16* __restrict__ A, const u16* __restrict__ W,
    const float* __restrict__ bias, float* __restrict__ out) {
    constexpr int K = 1024;
    __shared__ u16 sA[128 * 32];
    __shared__ u16 sB[128 * 32];
    const int t = threadIdx.x;
    const int wave = t >> 6, lane = t & 63;
    const int quad = lane >> 4, l16 = lane & 15;
    const int wr = wave >> 1, wc = wave & 1;
    const int m0 = blockIdx.x * 128;
    const int n0 = blockIdx.y * 128;

    floatx4 acc[4][4];
#pragma unroll
    for (int i = 0; i < 4; i++)
#pragma unroll
        for (int j = 0; j < 4; j++)
#pragma unroll
            for (int r = 0; r < 4; r++) acc[i][j][r] = 0.f;

    for (int k0 = 0; k0 < K; k0 += 32) {
        __syncthreads();
#pragma unroll
        for (int i = 0; i < 2; ++i) {
            const int idx = i * 256 + t;
            const int r_ = idx >> 2;
            const int c8 = (idx & 3) * 8;
            async_copy16(A + (size_t)(m0 + r_) * K + k0 + c8, &sA[r_ * 32 + c8]);
            async_copy16(W + (size_t)(n0 + r_) * K + k0 + c8, &sB[r_ * 32 + c8]);
        }
        __syncthreads();
        bf16x8 af[4], bw[4];
#pragma unroll
        for (int i = 0; i < 4; i++)
            af[i] = *(const bf16x8*)&sA[(wr * 64 + i * 16 + l16) * 32 + quad * 8];
#pragma unroll
        for (int j = 0; j < 4; j++)
            bw[j] = *(const bf16x8*)&sB[(wc * 64 + j * 16 + l16) * 32 + quad * 8];
#pragma unroll
        for (int i = 0; i < 4; i++)
#pragma unroll
            for (int j = 0; j < 4; j++)
                acc[i][j] = __builtin_amdgcn_mfma_f32_16x16x32_bf16(
                    af[i], bw[j], acc[i][j], 0, 0, 0);
    }
#pragma unroll
    for (int i = 0; i < 4; i++) {
#pragma unroll
        for (int j = 0; j < 4; j++) {
            const int n = n0 + wc * 64 + j * 16 + l16;
            const float bn = bias[n];
#pragma unroll
            for (int r = 0; r < 4; r++) {
                const int m = m0 + wr * 64 + i * 16 + quad * 4 + r;
                out[(size_t)m * 1024 + n] = acc[i][j][r] + bn;
            }
        }
    }
}

// ---- MFMA flash attention, S^T formulation, in-register P -------------------
// S^T = K Q^T via 16x16x32 bf16 (A=K, B=Q): C-layout lane=query m, reg=key
// quad*4+r. That reg mapping == the K=16 MFMA's B-operand k-mapping, so
// P = exp(S) feeds mfma_f32_16x16x16f16 (A = V^T f16, B = P f16) directly
// from registers — no LDS round-trip. O^T accumulates with lane=query,
// reg=e. l is a per-lane scalar partial, reduced across quads at the end.

__global__ __launch_bounds__(256, 3) void attn_mfma_kernel(
    const u16* __restrict__ qkv, const u16* __restrict__ Vt,
    u16* __restrict__ O) {
    __shared__ u16 sK[64 * 72];
    __shared__ u16 sV[64 * 72];   // f16 payload, [e][n] tile

    const int t = threadIdx.x;
    const int wave = t >> 6, lane = t & 63;
    const int quad = lane >> 4, l16 = lane & 15;
    const int id = blockIdx.x;                 // 0..511
    const int bh = (id & 7) + 8 * ((id >> 3) & 15);
    const int qb = id >> 7;                    // 0..3 (256 q-rows each)
    const size_t headoff = (size_t)bh * (1024 * 64);
    const u16* Qp = qkv + headoff;
    const u16* Kp = qkv + (size_t)128 * 1024 * 64 + headoff;
    const u16* Vtp = Vt + headoff;

    // Q B-frags for this wave's four 16-row q-sets (lane l16 = query)
    bf16x8 qf0[4], qf1[4];
#pragma unroll
    for (int qs = 0; qs < 4; ++qs) {
        const u16* qrow =
            Qp + (size_t)(qb * 256 + wave * 64 + qs * 16 + l16) * 64 + quad * 8;
        qf0[qs] = *(const bf16x8*)(qrow);
        qf1[qs] = *(const bf16x8*)(qrow + 32);
    }

    float l_part[4];
    floatx4 accO[4][4];   // [qs][et], O^T layout: lane=query, reg=e
#pragma unroll
    for (int qs = 0; qs < 4; ++qs) {
        l_part[qs] = 0.f;
#pragma unroll
        for (int et = 0; et < 4; ++et) accO[qs][et] = floatx4{0.f, 0.f, 0.f, 0.f};
    }

    // exp2 domain: p = 2^(s*0.125*log2e - 8*log2e)
    const float S2 = 0.18033688f;    // 0.125 * log2(e)
    const float B2 = -11.5415603f;   // -8 * log2(e)

    f16x4 pf[4][4];   // [qs][nt] P fragments (B-operand of PV)

    for (int kb = 0; kb < 16; ++kb) {
        __syncthreads();
        // stage K [n][e] and V^T [e][n] (f16), coalesced 8-lanes/row
#pragma unroll
        for (int it = 0; it < 2; ++it) {
            const int idx = it * 256 + t;
            const int row = idx >> 3, c8 = (idx & 7) * 8;
            uint4 uk = *(const uint4*)(Kp + (size_t)(kb * 64 + row) * 64 + c8);
            *(uint4*)(sK + row * 72 + c8) = uk;
            uint4 uv = *(const uint4*)(Vtp + (size_t)row * 1024 + kb * 64 + c8);
            *(uint4*)(sV + row * 72 + c8) = uv;
        }
        __syncthreads();

        // K A-frags (lane l16 = key), held across q-sets
        bf16x8 kf0[4], kf1[4];
#pragma unroll
        for (int nt = 0; nt < 4; ++nt) {
            const u16* krow = sK + (nt * 16 + l16) * 72 + quad * 8;
            kf0[nt] = *(const bf16x8*)(krow);
            kf1[nt] = *(const bf16x8*)(krow + 32);
        }

        // Phase A: S^T = K Q^T, exp2, pack P into registers
#pragma unroll
        for (int qs = 0; qs < 4; ++qs) {
            float lsum = 0.f;
#pragma unroll
            for (int nt = 0; nt < 4; ++nt) {
                floatx4 z = {0.f, 0.f, 0.f, 0.f};
                z = __builtin_amdgcn_mfma_f32_16x16x32_bf16(kf0[nt], qf0[qs], z, 0, 0, 0);
                z = __builtin_amdgcn_mfma_f32_16x16x32_bf16(kf1[nt], qf1[qs], z, 0, 0, 0);
                float p0 = __builtin_amdgcn_exp2f(fmaf(z[0], S2, B2));
                float p1 = __builtin_amdgcn_exp2f(fmaf(z[1], S2, B2));
                float p2 = __builtin_amdgcn_exp2f(fmaf(z[2], S2, B2));
                float p3 = __builtin_amdgcn_exp2f(fmaf(z[3], S2, B2));
                lsum += (p0 + p1) + (p2 + p3);
                pf[qs][nt] = pack4h(p0, p1, p2, p3);
            }
            l_part[qs] += lsum;
        }

        // Phase B: O^T += V^T P  (A = V^T f16 frags, B = P from registers)
#pragma unroll
        for (int et = 0; et < 4; ++et) {
#pragma unroll
            for (int nt = 0; nt < 4; ++nt) {
                f16x4 vf = *(const f16x4*)(sV + (et * 16 + l16) * 72 +
                                           nt * 16 + quad * 4);
#pragma unroll
                for (int qs = 0; qs < 4; ++qs)
                    accO[qs][et] = __builtin_amdgcn_mfma_f32_16x16x16f16(
                        vf, pf[qs][nt], accO[qs][et], 0, 0, 0);
            }
        }
    }

    // epilogue: l = sum over quads; O^T lane=query holds e=quad*4+r per et.
    const int b = bh >> 4, h = bh & 15;
#pragma unroll
    for (int qs = 0; qs < 4; ++qs) {
        float l = l_part[qs];
        l += __shfl_xor(l, 16);
        l += __shfl_xor(l, 32);
        const float inv = 1.f / l;
        const int q = qb * 256 + wave * 64 + qs * 16 + l16;
        u16* orow = O + (size_t)(b * 1024 + q) * 1024 + h * 64 + quad * 4;
#pragma unroll
        for (int et = 0; et < 4; ++et) {
            u32 r0 = (u32)f2b(accO[qs][et][0] * inv) |
                     ((u32)f2b(accO[qs][et][1] * inv) << 16);
            u32 r1 = (u32)f2b(accO[qs][et][2] * inv) |
                     ((u32)f2b(accO[qs][et][3] * inv) << 16);
            *(uint2*)(orow + et * 16) = make_uint2(r0, r1);
        }
    }
}

// ---- launch -----------------------------------------------------------------

extern "C" void kernel_launch(void* const* d_in, const int* in_sizes, int n_in,
                              void* d_out, int out_size, void* d_ws, size_t ws_size,
                              hipStream_t stream) {
    const float* x     = (const float*)d_in[0];   // [8,1024,1024]
    const float* Wqkv  = (const float*)d_in[1];   // [3072,1024]
    const float* Wproj = (const float*)d_in[2];   // [1024,1024]
    const float* bproj = (const float*)d_in[3];   // [1024]
    float* out = (float*)d_out;

    char* ws = (char*)d_ws;
    u16* xb     = (u16*)(ws);                            // 16 MiB
    u16* wqkvb  = (u16*)(ws + (16ull << 20));            // 6 MiB
    u16* wprojb = (u16*)(ws + (22ull << 20));            // 2 MiB
    u16* qkvsep = (u16*)(ws + (24ull << 20));            // Q,K: [2][8][16][1024][64]
    u16* vtb    = (u16*)(ws + (72ull << 20));            // 16 MiB f16: [8][16][64][1024]
    u16* Ob     = (u16*)(ws + (88ull << 20));            // 16 MiB: [8][1024][1024]

    cast_all_kernel<<<12288, 256, 0, stream>>>(
        (const float4*)x, (const float4*)Wqkv, (const float4*)Wproj,
        (ushort4*)xb, (ushort4*)wqkvb, (ushort4*)wprojb);

    gemm_qkv_kernel<<<dim3(64, 24), 256, 0, stream>>>(xb, wqkvb, qkvsep, vtb);
    attn_mfma_kernel<<<512, 256, 0, stream>>>(qkvsep, vtb, Ob);
    gemm_proj_kernel<<<dim3(64, 8), 256, 0, stream>>>(Ob, wprojb, bproj, out);
}

// Round 7
// 240.903 us; speedup vs baseline: 1.1239x; 1.1239x over previous
//
#include <hip/hip_runtime.h>

typedef unsigned int u32;
typedef unsigned short u16;
typedef __bf16 bf16x8 __attribute__((ext_vector_type(8)));
typedef float floatx4 __attribute__((ext_vector_type(4)));
typedef _Float16 f16x4 __attribute__((ext_vector_type(4)));

// ---- helpers ----------------------------------------------------------------

// fp32 -> bf16 bits, round-to-nearest-even
__device__ __forceinline__ u16 f2b(float f) {
    u32 u = __float_as_uint(f);
    u = u + 0x7fffu + ((u >> 16) & 1u);
    return (u16)(u >> 16);
}

// pack 4 fp32 -> f16x4 via scalar v_cvt_f16_f32
__device__ __forceinline__ f16x4 pack4h(float a, float b, float c, float d) {
    f16x4 v;
    v[0] = (_Float16)a; v[1] = (_Float16)b;
    v[2] = (_Float16)c; v[3] = (_Float16)d;
    return v;
}

// pack 2 fp32 -> u32 of 2 bf16
__device__ __forceinline__ u32 pack2b(float a, float b) {
    return (u32)f2b(a) | ((u32)f2b(b) << 16);
}

// async global->LDS 16B copy (lane-linear LDS dest required)
__device__ __forceinline__ void async_copy16(const void* g, void* l) {
    __builtin_amdgcn_global_load_lds(
        (__attribute__((address_space(1))) u32*)g,
        (__attribute__((address_space(3))) u32*)l, 16, 0, 0);
}

// ---- merged cast kernel -----------------------------------------------------
// x: 2097152 float4 | Wqkv: 786432 | Wproj: 262144  (total 3145728)

__global__ void cast_all_kernel(const float4* __restrict__ x,
                                const float4* __restrict__ wq,
                                const float4* __restrict__ wp,
                                ushort4* __restrict__ xb,
                                ushort4* __restrict__ wqb,
                                ushort4* __restrict__ wpb) {
    int i = blockIdx.x * 256 + threadIdx.x;
    const float4* s;
    ushort4* d;
    int off;
    if (i < 2097152) { s = x; d = xb; off = i; }
    else if (i < 2883584) { s = wq; d = wqb; off = i - 2097152; }
    else { s = wp; d = wpb; off = i - 2883584; }
    float4 v = s[off];
    ushort4 o;
    o.x = f2b(v.x); o.y = f2b(v.y); o.z = f2b(v.z); o.w = f2b(v.w);
    d[off] = o;
}

// ---- GEMM 1a: Q,K thirds, swapped operands ----------------------------------
// A = Wqkv rows (features m, 0..2047), B = x rows (tokens n).
// C[m=feature][n=token]: lane l16 = token, regs quad*4+r = 4 consecutive
// features -> one 8-B packed bf16x4 store per (i,j) into natural
// qkvsep [tsel][b][h][nn][e].

__global__ __launch_bounds__(256) void gemm_qk_kernel(
    const u16* __restrict__ X, const u16* __restrict__ W,
    u16* __restrict__ qkvsep) {
    constexpr int K = 1024;
    __shared__ u16 sA[128 * 32];
    __shared__ u16 sB[128 * 32];
    const int t = threadIdx.x;
    const int wave = t >> 6, lane = t & 63;
    const int quad = lane >> 4, l16 = lane & 15;
    const int wr = wave >> 1, wc = wave & 1;
    const int m0 = blockIdx.x * 128;   // feature base (0..2047)
    const int n0 = blockIdx.y * 128;   // token base (0..8191)

    floatx4 acc[4][4];
#pragma unroll
    for (int i = 0; i < 4; i++)
#pragma unroll
        for (int j = 0; j < 4; j++)
#pragma unroll
            for (int r = 0; r < 4; r++) acc[i][j][r] = 0.f;

    for (int k0 = 0; k0 < K; k0 += 32) {
        __syncthreads();
#pragma unroll
        for (int i = 0; i < 2; ++i) {
            const int idx = i * 256 + t;
            const int r_ = idx >> 2;
            const int c8 = (idx & 3) * 8;
            async_copy16(W + (size_t)(m0 + r_) * K + k0 + c8, &sA[r_ * 32 + c8]);
            async_copy16(X + (size_t)(n0 + r_) * K + k0 + c8, &sB[r_ * 32 + c8]);
        }
        __syncthreads();
        bf16x8 af[4], bw[4];
#pragma unroll
        for (int i = 0; i < 4; i++)
            af[i] = *(const bf16x8*)&sA[(wr * 64 + i * 16 + l16) * 32 + quad * 8];
#pragma unroll
        for (int j = 0; j < 4; j++)
            bw[j] = *(const bf16x8*)&sB[(wc * 64 + j * 16 + l16) * 32 + quad * 8];
#pragma unroll
        for (int i = 0; i < 4; i++)
#pragma unroll
            for (int j = 0; j < 4; j++)
                acc[i][j] = __builtin_amdgcn_mfma_f32_16x16x32_bf16(
                    af[i], bw[j], acc[i][j], 0, 0, 0);
    }
    // epilogue: 8-B packed stores, natural layout
#pragma unroll
    for (int i = 0; i < 4; i++) {
        const int feat = m0 + wr * 64 + i * 16 + quad * 4;
        const int tsel = feat >> 10, h = (feat >> 6) & 15, e = feat & 63;
#pragma unroll
        for (int j = 0; j < 4; j++) {
            const int token = n0 + wc * 64 + j * 16 + l16;
            const int b = token >> 10, nn = token & 1023;
            u16* dst = qkvsep +
                ((((size_t)tsel * 8 + b) * 16 + h) * 1024 + nn) * 64 + e;
            *(uint2*)dst = make_uint2(pack2b(acc[i][j][0], acc[i][j][1]),
                                      pack2b(acc[i][j][2], acc[i][j][3]));
        }
    }
}

// ---- GEMM 1b: V third -> Vt [8][16][64][1024] f16 (transposed, 8B stores) ---

__global__ __launch_bounds__(256) void gemm_v_kernel(
    const u16* __restrict__ A, const u16* __restrict__ W,
    u16* __restrict__ Vt) {
    constexpr int K = 1024;
    __shared__ u16 sA[128 * 32];
    __shared__ u16 sB[128 * 32];
    const int t = threadIdx.x;
    const int wave = t >> 6, lane = t & 63;
    const int quad = lane >> 4, l16 = lane & 15;
    const int wr = wave >> 1, wc = wave & 1;
    const int m0 = blockIdx.x * 128;          // token base
    const int n0 = 2048 + blockIdx.y * 128;   // V feature base

    floatx4 acc[4][4];
#pragma unroll
    for (int i = 0; i < 4; i++)
#pragma unroll
        for (int j = 0; j < 4; j++)
#pragma unroll
            for (int r = 0; r < 4; r++) acc[i][j][r] = 0.f;

    for (int k0 = 0; k0 < K; k0 += 32) {
        __syncthreads();
#pragma unroll
        for (int i = 0; i < 2; ++i) {
            const int idx = i * 256 + t;
            const int r_ = idx >> 2;
            const int c8 = (idx & 3) * 8;
            async_copy16(A + (size_t)(m0 + r_) * K + k0 + c8, &sA[r_ * 32 + c8]);
            async_copy16(W + (size_t)(n0 + r_) * K + k0 + c8, &sB[r_ * 32 + c8]);
        }
        __syncthreads();
        bf16x8 af[4], bw[4];
#pragma unroll
        for (int i = 0; i < 4; i++)
            af[i] = *(const bf16x8*)&sA[(wr * 64 + i * 16 + l16) * 32 + quad * 8];
#pragma unroll
        for (int j = 0; j < 4; j++)
            bw[j] = *(const bf16x8*)&sB[(wc * 64 + j * 16 + l16) * 32 + quad * 8];
#pragma unroll
        for (int i = 0; i < 4; i++)
#pragma unroll
            for (int j = 0; j < 4; j++)
                acc[i][j] = __builtin_amdgcn_mfma_f32_16x16x32_bf16(
                    af[i], bw[j], acc[i][j], 0, 0, 0);
    }
    // V: write transposed f16 Vt[bh][e][n], 8-B stores
#pragma unroll
    for (int i = 0; i < 4; i++) {
#pragma unroll
        for (int j = 0; j < 4; j++) {
            const int n = n0 + wc * 64 + j * 16 + l16;
            const int h = (n >> 6) & 15, e = n & 63;
            const int m = m0 + wr * 64 + i * 16 + quad * 4;
            const int b = m >> 10, nn = m & 1023;
            f16x4 v = pack4h(acc[i][j][0], acc[i][j][1],
                             acc[i][j][2], acc[i][j][3]);
            *(f16x4*)(Vt + (((size_t)(b * 16 + h) * 64 + e) * 1024 + nn)) = v;
        }
    }
}

// ---- GEMM 2: out = O @ Wproj^T + bias, fp32 out -----------------------------

__global__ __launch_bounds__(256) void gemm_proj_kernel(
    const u16* __restrict__ A, const u16* __restrict__ W,
    const float* __restrict__ bias, float* __restrict__ out) {
    constexpr int K = 1024;
    __shared__ u16 sA[128 * 32];
    __shared__ u16 sB[128 * 32];
    const int t = threadIdx.x;
    const int wave = t >> 6, lane = t & 63;
    const int quad = lane >> 4, l16 = lane & 15;
    const int wr = wave >> 1, wc = wave & 1;
    const int m0 = blockIdx.x * 128;
    const int n0 = blockIdx.y * 128;

    floatx4 acc[4][4];
#pragma unroll
    for (int i = 0; i < 4; i++)
#pragma unroll
        for (int j = 0; j < 4; j++)
#pragma unroll
            for (int r = 0; r < 4; r++) acc[i][j][r] = 0.f;

    for (int k0 = 0; k0 < K; k0 += 32) {
        __syncthreads();
#pragma unroll
        for (int i = 0; i < 2; ++i) {
            const int idx = i * 256 + t;
            const int r_ = idx >> 2;
            const int c8 = (idx & 3) * 8;
            async_copy16(A + (size_t)(m0 + r_) * K + k0 + c8, &sA[r_ * 32 + c8]);
            async_copy16(W + (size_t)(n0 + r_) * K + k0 + c8, &sB[r_ * 32 + c8]);
        }
        __syncthreads();
        bf16x8 af[4], bw[4];
#pragma unroll
        for (int i = 0; i < 4; i++)
            af[i] = *(const bf16x8*)&sA[(wr * 64 + i * 16 + l16) * 32 + quad * 8];
#pragma unroll
        for (int j = 0; j < 4; j++)
            bw[j] = *(const bf16x8*)&sB[(wc * 64 + j * 16 + l16) * 32 + quad * 8];
#pragma unroll
        for (int i = 0; i < 4; i++)
#pragma unroll
            for (int j = 0; j < 4; j++)
                acc[i][j] = __builtin_amdgcn_mfma_f32_16x16x32_bf16(
                    af[i], bw[j], acc[i][j], 0, 0, 0);
    }
#pragma unroll
    for (int i = 0; i < 4; i++) {
#pragma unroll
        for (int j = 0; j < 4; j++) {
            const int n = n0 + wc * 64 + j * 16 + l16;
            const float bn = bias[n];
#pragma unroll
            for (int r = 0; r < 4; r++) {
                const int m = m0 + wr * 64 + i * 16 + quad * 4 + r;
                out[(size_t)m * 1024 + n] = acc[i][j][r] + bn;
            }
        }
    }
}

// ---- MFMA flash attention, S^T formulation, in-register P -------------------
// Same as round 6 but __launch_bounds__(256,2): the 512-block grid caps
// residency at 2 blocks/CU anyway, and the (256,3) VGPR budget (~170) forced
// ~75 MB of scratch spill traffic (WRITE_SIZE 91 MB vs 16 MB of O).

__global__ __launch_bounds__(256, 2) void attn_mfma_kernel(
    const u16* __restrict__ qkv, const u16* __restrict__ Vt,
    u16* __restrict__ O) {
    __shared__ u16 sK[64 * 72];
    __shared__ u16 sV[64 * 72];   // f16 payload, [e][n] tile

    const int t = threadIdx.x;
    const int wave = t >> 6, lane = t & 63;
    const int quad = lane >> 4, l16 = lane & 15;
    const int id = blockIdx.x;                 // 0..511
    const int bh = (id & 7) + 8 * ((id >> 3) & 15);
    const int qb = id >> 7;                    // 0..3 (256 q-rows each)
    const size_t headoff = (size_t)bh * (1024 * 64);
    const u16* Qp = qkv + headoff;
    const u16* Kp = qkv + (size_t)128 * 1024 * 64 + headoff;
    const u16* Vtp = Vt + headoff;

    // Q B-frags for this wave's four 16-row q-sets (lane l16 = query)
    bf16x8 qf0[4], qf1[4];
#pragma unroll
    for (int qs = 0; qs < 4; ++qs) {
        const u16* qrow =
            Qp + (size_t)(qb * 256 + wave * 64 + qs * 16 + l16) * 64 + quad * 8;
        qf0[qs] = *(const bf16x8*)(qrow);
        qf1[qs] = *(const bf16x8*)(qrow + 32);
    }

    float l_part[4];
    floatx4 accO[4][4];   // [qs][et], O^T layout: lane=query, reg=e
#pragma unroll
    for (int qs = 0; qs < 4; ++qs) {
        l_part[qs] = 0.f;
#pragma unroll
        for (int et = 0; et < 4; ++et) accO[qs][et] = floatx4{0.f, 0.f, 0.f, 0.f};
    }

    // exp2 domain: p = 2^(s*0.125*log2e - 8*log2e)
    const float S2 = 0.18033688f;    // 0.125 * log2(e)
    const float B2 = -11.5415603f;   // -8 * log2(e)

    f16x4 pf[4][4];   // [qs][nt] P fragments (B-operand of PV)

    for (int kb = 0; kb < 16; ++kb) {
        __syncthreads();
        // stage K [n][e] and V^T [e][n] (f16), coalesced 8-lanes/row
#pragma unroll
        for (int it = 0; it < 2; ++it) {
            const int idx = it * 256 + t;
            const int row = idx >> 3, c8 = (idx & 7) * 8;
            uint4 uk = *(const uint4*)(Kp + (size_t)(kb * 64 + row) * 64 + c8);
            *(uint4*)(sK + row * 72 + c8) = uk;
            uint4 uv = *(const uint4*)(Vtp + (size_t)row * 1024 + kb * 64 + c8);
            *(uint4*)(sV + row * 72 + c8) = uv;
        }
        __syncthreads();

        // K A-frags (lane l16 = key), held across q-sets
        bf16x8 kf0[4], kf1[4];
#pragma unroll
        for (int nt = 0; nt < 4; ++nt) {
            const u16* krow = sK + (nt * 16 + l16) * 72 + quad * 8;
            kf0[nt] = *(const bf16x8*)(krow);
            kf1[nt] = *(const bf16x8*)(krow + 32);
        }

        // Phase A: S^T = K Q^T, exp2, pack P into registers
#pragma unroll
        for (int qs = 0; qs < 4; ++qs) {
            float lsum = 0.f;
#pragma unroll
            for (int nt = 0; nt < 4; ++nt) {
                floatx4 z = {0.f, 0.f, 0.f, 0.f};
                z = __builtin_amdgcn_mfma_f32_16x16x32_bf16(kf0[nt], qf0[qs], z, 0, 0, 0);
                z = __builtin_amdgcn_mfma_f32_16x16x32_bf16(kf1[nt], qf1[qs], z, 0, 0, 0);
                float p0 = __builtin_amdgcn_exp2f(fmaf(z[0], S2, B2));
                float p1 = __builtin_amdgcn_exp2f(fmaf(z[1], S2, B2));
                float p2 = __builtin_amdgcn_exp2f(fmaf(z[2], S2, B2));
                float p3 = __builtin_amdgcn_exp2f(fmaf(z[3], S2, B2));
                lsum += (p0 + p1) + (p2 + p3);
                pf[qs][nt] = pack4h(p0, p1, p2, p3);
            }
            l_part[qs] += lsum;
        }

        // Phase B: O^T += V^T P  (A = V^T f16 frags, B = P from registers)
#pragma unroll
        for (int et = 0; et < 4; ++et) {
#pragma unroll
            for (int nt = 0; nt < 4; ++nt) {
                f16x4 vf = *(const f16x4*)(sV + (et * 16 + l16) * 72 +
                                           nt * 16 + quad * 4);
#pragma unroll
                for (int qs = 0; qs < 4; ++qs)
                    accO[qs][et] = __builtin_amdgcn_mfma_f32_16x16x16f16(
                        vf, pf[qs][nt], accO[qs][et], 0, 0, 0);
            }
        }
    }

    // epilogue: l = sum over quads; O^T lane=query holds e=quad*4+r per et.
    const int b = bh >> 4, h = bh & 15;
#pragma unroll
    for (int qs = 0; qs < 4; ++qs) {
        float l = l_part[qs];
        l += __shfl_xor(l, 16);
        l += __shfl_xor(l, 32);
        const float inv = 1.f / l;
        const int q = qb * 256 + wave * 64 + qs * 16 + l16;
        u16* orow = O + (size_t)(b * 1024 + q) * 1024 + h * 64 + quad * 4;
#pragma unroll
        for (int et = 0; et < 4; ++et) {
            u32 r0 = pack2b(accO[qs][et][0] * inv, accO[qs][et][1] * inv);
            u32 r1 = pack2b(accO[qs][et][2] * inv, accO[qs][et][3] * inv);
            *(uint2*)(orow + et * 16) = make_uint2(r0, r1);
        }
    }
}

// ---- launch -----------------------------------------------------------------

extern "C" void kernel_launch(void* const* d_in, const int* in_sizes, int n_in,
                              void* d_out, int out_size, void* d_ws, size_t ws_size,
                              hipStream_t stream) {
    const float* x     = (const float*)d_in[0];   // [8,1024,1024]
    const float* Wqkv  = (const float*)d_in[1];   // [3072,1024]
    const float* Wproj = (const float*)d_in[2];   // [1024,1024]
    const float* bproj = (const float*)d_in[3];   // [1024]
    float* out = (float*)d_out;

    char* ws = (char*)d_ws;
    u16* xb     = (u16*)(ws);                            // 16 MiB
    u16* wqkvb  = (u16*)(ws + (16ull << 20));            // 6 MiB
    u16* wprojb = (u16*)(ws + (22ull << 20));            // 2 MiB
    u16* qkvsep = (u16*)(ws + (24ull << 20));            // Q,K: [2][8][16][1024][64]
    u16* vtb    = (u16*)(ws + (72ull << 20));            // 16 MiB f16: [8][16][64][1024]
    u16* Ob     = (u16*)(ws + (88ull << 20));            // 16 MiB: [8][1024][1024]

    cast_all_kernel<<<12288, 256, 0, stream>>>(
        (const float4*)x, (const float4*)Wqkv, (const float4*)Wproj,
        (ushort4*)xb, (ushort4*)wqkvb, (ushort4*)wprojb);

    gemm_qk_kernel<<<dim3(16, 64), 256, 0, stream>>>(xb, wqkvb, qkvsep);
    gemm_v_kernel<<<dim3(64, 8), 256, 0, stream>>>(xb, wqkvb, vtb);
    attn_mfma_kernel<<<512, 256, 0, stream>>>(qkvsep, vtb, Ob);
    gemm_proj_kernel<<<dim3(64, 8), 256, 0, stream>>>(Ob, wprojb, bproj, out);
}